// Round 3
// baseline (222.458 us; speedup 1.0000x reference)
//
#include <hip/hip_runtime.h>

// QuantizedLinear(5, 10, bits=2): out[N,10] = x[N,5] @ w_deq.T + bias
// Memory-bound: 80 MB read + 160 MB write -> ~38 us floor @ 6.3 TB/s.
//
// R1 (225): 60KB LDS, 2 blk/CU.  R2 (237): lane-strided direct, 5x txns.
// R3 (211.6): coalesced scalar, 8 blk/CU, NT.  R4 (219.3): float4 staged,
//   5 blk/CU, no NT. Lesson: VMEM width + occupancy moved nothing (+-4%)
//   -> not issue-bound. Remaining suspect (T_B): per-block phase
//   serialization — every __syncthreads drains vmcnt(0), chopping the
//   global stream into per-tile bursts; 15625 short-lived blocks also
//   re-dequantize w. Alternative (T_A): kernel already ~50us and the rest
//   of dur_us is harness-fixed; then nothing moves and we're at roofline.
// R5: persistent double-buffered pipeline (counted vmcnt, raw s_barrier).
//   Container failed twice — likely infra (R4 logs showed 26-min pushes),
//   but R5 also had one unverified construct: global_load_lds under a
//   partial exec mask (lane<16).
// R6 (this): same probe, hardened. All global_load_lds are width-4 with
//   full 64-lane exec (5 per wave per tile); staging path block-uniform
//   per tile. Steady-state wait vmcnt(3): queue at barrier A is
//   [5 staging (oldest) | 3 NT stores (newest)] per wave — staging
//   retires, stores stay in flight across the barrier. Weights
//   dequantized once per block. LDS 20.7 KB -> 7 blk/CU (28 waves).

typedef float f32x4 __attribute__((ext_vector_type(4)));

constexpr int IN_F  = 5;
constexpr int OUT_F = 10;
constexpr int BLOCK = 256;
constexpr int TOK   = 256;                 // tokens per tile
constexpr int TDWX  = TOK * IN_F;          // 1280 x dwords per tile
constexpr int WDWX  = TDWX / 4;            // 320 x dwords per wave
constexpr int OCH   = TOK * OUT_F / 4;     // 640 out f4-chunks per tile
constexpr int WOCH  = OCH / 4;             // 160 out f4-chunks per wave
constexpr int GRID  = 2048;                // persistent blocks

typedef __attribute__((address_space(3))) void       lds_void;
typedef __attribute__((address_space(1))) const void gbl_void;

__global__ __launch_bounds__(BLOCK) void qlinear_kernel(
    const float* __restrict__ x,
    const float* __restrict__ w,
    const float* __restrict__ bias,
    float* __restrict__ out,
    int n_tokens)
{
    __shared__ float wdq[OUT_F * IN_F];
    __shared__ float bsh[OUT_F];
    __shared__ __align__(16) float xs[2][TDWX];         // 2 x 5 KB
    __shared__ __align__(16) float os[TOK * OUT_F];     // 10 KB

    const int tid  = threadIdx.x;
    const int wid  = tid >> 6;
    const int lane = tid & 63;

    const long ntile = ((long)n_tokens + TOK - 1) / TOK;   // 15625
    const long xtot  = (long)n_tokens * IN_F;
    const long otot  = (long)n_tokens * OUT_F;

    long tile = blockIdx.x;
    if (tile >= ntile) return;   // grid <= ntile: never taken; barriers uniform

    // dequantize once per persistent block (tid 0..9, one row each)
    if (tid < OUT_F) {
        float row[IN_F];
        float mx = 0.0f;
        #pragma unroll
        for (int j = 0; j < IN_F; ++j) {
            row[j] = w[tid * IN_F + j];
            mx = fmaxf(mx, fabsf(row[j]));
        }
        const float scale = fmaxf(mx, 1e-8f);
        #pragma unroll
        for (int j = 0; j < IN_F; ++j) {
            float q = rintf(row[j] / scale);      // round-half-even like jnp
            q = fminf(fmaxf(q, -2.0f), 1.0f);
            wdq[tid * IN_F + j] = q * scale;
        }
        bsh[tid] = bias[tid];
    }

    // full-tile staging: 5 x width-4 global_load_lds, full exec, per wave.
    // LDS dest is wave-uniform base + lane*4 (linear); global src per-lane.
    auto stageDMA = [&](long t, int b) {
        const long g0 = t * TDWX + (long)(wid * WDWX);
        float* dst = &xs[b][wid * WDWX];
        #pragma unroll
        for (int i = 0; i < 5; ++i) {
            __builtin_amdgcn_global_load_lds(
                (gbl_void*)(x + g0 + i * 64 + lane),
                (lds_void*)(dst + i * 64), 4, 0, 0);
        }
    };
    // tail-tile staging: bounds-checked scalar loads + plain LDS writes
    auto stageScalar = [&](long t, int b) {
        const long g0 = t * TDWX + (long)(wid * WDWX);
        float* dst = &xs[b][wid * WDWX];
        #pragma unroll
        for (int i = 0; i < 5; ++i) {
            const long gi = g0 + i * 64 + lane;
            dst[i * 64 + lane] = (gi < xtot) ? x[gi] : 0.0f;
        }
    };

    // prologue: stage tile 0 for this block
    bool staged_dma = ((tile + 1) * (long)TOK <= (long)n_tokens);
    if (staged_dma) stageDMA(tile, 0); else stageScalar(tile, 0);
    int  buf   = 0;
    bool first = true;

    for (; tile < ntile; tile += GRID) {
        const long nxt = tile + GRID;

        // A: wait for xs[buf]'s staging. Steady state: the 3 newest vmem
        // ops are the previous store burst (allowed to stay in flight);
        // everything older (this tile's 5 staging ops) retires.
        if (first || !staged_dma) {
            asm volatile("s_waitcnt vmcnt(0)" ::: "memory");
        } else {
            asm volatile("s_waitcnt vmcnt(3)" ::: "memory");
        }
        asm volatile("s_waitcnt lgkmcnt(0)" ::: "memory");
        __builtin_amdgcn_s_barrier();              // xs[buf] ready, os free
        __builtin_amdgcn_sched_barrier(0);
        first = false;

        // compute: 1 token/thread; xs read stride 5 (2-way = free);
        // os write stride 10 (4-way, short phase, negligible)
        {
            float xv[IN_F];
            #pragma unroll
            for (int j = 0; j < IN_F; ++j) xv[j] = xs[buf][tid * IN_F + j];
            #pragma unroll
            for (int o = 0; o < OUT_F; ++o) {
                float acc = bsh[o];
                #pragma unroll
                for (int c = 0; c < IN_F; ++c)
                    acc = fmaf(xv[c], wdq[o * IN_F + c], acc);
                os[tid * OUT_F + o] = acc;
            }
        }
        asm volatile("s_waitcnt lgkmcnt(0)" ::: "memory");
        __builtin_amdgcn_s_barrier();              // os ready
        __builtin_amdgcn_sched_barrier(0);

        // issue next tile's staging before the store burst
        if (nxt < ntile) {
            staged_dma = ((nxt + 1) * (long)TOK <= (long)n_tokens);
            if (staged_dma) stageDMA(nxt, buf ^ 1);
            else            stageScalar(nxt, buf ^ 1);
        }

        // store burst: 3 NT b128 per wave (64+64+32 lanes), coalesced
        {
            const long oc0 = tile * (long)OCH + (long)(wid * WOCH);
            const f32x4* os4 = (const f32x4*)os;
            f32x4* og4 = (f32x4*)out;
            #pragma unroll
            for (int i = 0; i < 3; ++i) {
                const int nact = (i == 2) ? 32 : 64;
                if (lane < nact) {
                    const int  lc = wid * WOCH + i * 64 + lane;
                    const long gc = oc0 + i * 64 + lane;
                    const f32x4 v = os4[lc];
                    if ((gc + 1) * 4 <= otot) {
                        __builtin_nontemporal_store(v, og4 + gc);
                    } else {                         // tail tile only
                        #pragma unroll
                        for (int e = 0; e < 4; ++e) {
                            const long gi = gc * 4 + e;
                            if (gi < otot) out[gi] = v[e];
                        }
                    }
                }
            }
        }
        buf ^= 1;
    }
}

extern "C" void kernel_launch(void* const* d_in, const int* in_sizes, int n_in,
                              void* d_out, int out_size, void* d_ws, size_t ws_size,
                              hipStream_t stream) {
    const float* x    = (const float*)d_in[0];   // [N, 5]
    const float* wgt  = (const float*)d_in[1];   // [10, 5]
    const float* bias = (const float*)d_in[2];   // [10]
    float* out = (float*)d_out;                  // [N, 10]

    const int  n_tokens = in_sizes[0] / IN_F;    // 4,000,000
    const long ntile    = ((long)n_tokens + TOK - 1) / TOK;
    const int  blocks   = (int)(ntile < (long)GRID ? ntile : (long)GRID);

    qlinear_kernel<<<blocks, BLOCK, 0, stream>>>(x, wgt, bias, out, n_tokens);
}